// Round 1
// baseline (352.878 us; speedup 1.0000x reference)
//
#include <hip/hip_runtime.h>
#include <math.h>

#define D_MODEL 2048
#define KB_ 64
#define WW 512
#define NCHUNK 32

// workspace layout (float offsets)
#define N_COEFFS (NCHUNK*KB_*D_MODEL)           // 4,194,304
#define OFF_NORMS (N_COEFFS)                    // 2048 entries
#define OFF_VR (OFF_NORMS + NCHUNK*KB_)
#define OFF_VI (OFF_VR + D_MODEL)
#define OFF_CTX (OFF_VI + D_MODEL)

// ---------------------------------------------------------------------------
// K1: coeffs[c][k][d] = scale * sum_n cheby[k][n] * window_c[n][d]
// window_c = [chunk_{c-1}; chunk_c], chunk_{-1} = buf[256:512]
// chunk_c[n][d] = 0.5*(scan[0][c*256+n][d] + scan[1][c*256+n][d])
// grid: (16 d-tiles of 128, 32 windows), 256 threads
// ---------------------------------------------------------------------------
__global__ __launch_bounds__(256) void k1_coeffs(
    const float* __restrict__ scan, const float* __restrict__ buf,
    const float* __restrict__ cheby, float* __restrict__ coeffs)
{
  __shared__ float data_s[64 * 132];  // [n][128d], stride 132 (16B-aligned rows)
  __shared__ float cheb_s[64 * 68];   // [k][64n], stride 68

  const int tid = threadIdx.x;
  const int c = blockIdx.y;
  const int dtile = blockIdx.x;
  const int qd = tid & 31;        // d-quad index (0..31)
  const int kg = tid >> 5;        // k-group (0..7), 8 k's each
  const int col = dtile * 128 + qd * 4;

  float4 acc[8];
#pragma unroll
  for (int j = 0; j < 8; ++j) acc[j] = make_float4(0.f, 0.f, 0.f, 0.f);

  const float* scan1 = scan + 8192 * 2048;

  for (int nb = 0; nb < 8; ++nb) {
    __syncthreads();
    // stage 64 window-rows x 128 cols of data
#pragma unroll
    for (int i = 0; i < 8; ++i) {
      int flat = tid + i * 256;      // 0..2047
      int nl = flat >> 5;            // 0..63
      int qq = flat & 31;
      int wn = nb * 64 + nl;         // window n (0..511); wn<256 uniform per nb
      int ccol = dtile * 128 + qq * 4;
      float4 v;
      if (c == 0 && wn < 256) {
        v = *(const float4*)(buf + (256 + wn) * D_MODEL + ccol);
      } else {
        int s = (wn < 256) ? (c - 1) : c;
        int r = (wn < 256) ? wn : wn - 256;
        int off = (s * 256 + r) * D_MODEL + ccol;
        float4 a = *(const float4*)(scan + off);
        float4 b = *(const float4*)(scan1 + off);
        v = make_float4(0.5f * (a.x + b.x), 0.5f * (a.y + b.y),
                        0.5f * (a.z + b.z), 0.5f * (a.w + b.w));
      }
      *(float4*)(data_s + nl * 132 + qq * 4) = v;
    }
    // stage cheby[64k][64n] for this n-block
#pragma unroll
    for (int i = 0; i < 4; ++i) {
      int flat = tid + i * 256;      // 0..1023
      int k = flat >> 4;
      int qn = flat & 15;
      float4 v = *(const float4*)(cheby + k * 512 + nb * 64 + qn * 4);
      *(float4*)(cheb_s + k * 68 + qn * 4) = v;
    }
    __syncthreads();

#pragma unroll 2
    for (int nn = 0; nn < 64; nn += 4) {
      float4 d0 = *(const float4*)(data_s + (nn + 0) * 132 + qd * 4);
      float4 d1 = *(const float4*)(data_s + (nn + 1) * 132 + qd * 4);
      float4 d2 = *(const float4*)(data_s + (nn + 2) * 132 + qd * 4);
      float4 d3 = *(const float4*)(data_s + (nn + 3) * 132 + qd * 4);
#pragma unroll
      for (int j = 0; j < 8; ++j) {
        float4 cv = *(const float4*)(cheb_s + (kg * 8 + j) * 68 + nn);
        acc[j].x += cv.x * d0.x + cv.y * d1.x + cv.z * d2.x + cv.w * d3.x;
        acc[j].y += cv.x * d0.y + cv.y * d1.y + cv.z * d2.y + cv.w * d3.y;
        acc[j].z += cv.x * d0.z + cv.y * d1.z + cv.z * d2.z + cv.w * d3.z;
        acc[j].w += cv.x * d0.w + cv.y * d1.w + cv.z * d2.w + cv.w * d3.w;
      }
    }
  }

  const float scale = 2.0f / 512.0f;
#pragma unroll
  for (int j = 0; j < 8; ++j) {
    int k = kg * 8 + j;
    float sc = (k == 0) ? scale * 0.5f : scale;
    float4 o = make_float4(acc[j].x * sc, acc[j].y * sc, acc[j].z * sc, acc[j].w * sc);
    *(float4*)(coeffs + (c * KB_ + k) * D_MODEL + col) = o;
  }
}

// ---------------------------------------------------------------------------
// K2: blocks 0..2047 -> norms[c][k] = max(||coeffs[c][k][:]||, 1e-12)
//     blocks 2048..2111 -> delta[k] = ||coeffs[31][k]-coeffs[30][k]|| -> d_out
// ---------------------------------------------------------------------------
__global__ __launch_bounds__(256) void k2_norms(
    const float* __restrict__ coeffs, float* __restrict__ norms,
    float* __restrict__ dout)
{
  const int tid = threadIdx.x;
  const int b = blockIdx.x;
  float s = 0.f;
  if (b < NCHUNK * KB_) {
    const float* p = coeffs + b * D_MODEL;
#pragma unroll
    for (int i = 0; i < 2; ++i) {
      float4 v = *(const float4*)(p + tid * 4 + i * 1024);
      s += v.x * v.x + v.y * v.y + v.z * v.z + v.w * v.w;
    }
  } else {
    int k = b - NCHUNK * KB_;
    const float* p1 = coeffs + (31 * KB_ + k) * D_MODEL;
    const float* p0 = coeffs + (30 * KB_ + k) * D_MODEL;
#pragma unroll
    for (int i = 0; i < 2; ++i) {
      float4 a = *(const float4*)(p1 + tid * 4 + i * 1024);
      float4 bb = *(const float4*)(p0 + tid * 4 + i * 1024);
      float dx = a.x - bb.x, dy = a.y - bb.y, dz = a.z - bb.z, dw = a.w - bb.w;
      s += dx * dx + dy * dy + dz * dz + dw * dw;
    }
  }
  for (int o = 32; o > 0; o >>= 1) s += __shfl_down(s, o, 64);
  __shared__ float red[4];
  if ((tid & 63) == 0) red[tid >> 6] = s;
  __syncthreads();
  if (tid == 0) {
    float t = red[0] + red[1] + red[2] + red[3];
    float r = sqrtf(t);
    if (b < NCHUNK * KB_) norms[b] = fmaxf(r, 1e-12f);
    else dout[D_MODEL + (b - NCHUNK * KB_)] = r;
  }
}

// ---------------------------------------------------------------------------
// K3: vr[d] += 0.1*0.9^(31-c) * sum_k (coeffs[c][k][d]/norms[c][k])*roles[k][d]
// grid: (8 d-tiles of 256, 32 c), atomics into zeroed vr/vi
// ---------------------------------------------------------------------------
__global__ __launch_bounds__(256) void k3_bind(
    const float* __restrict__ coeffs, const float* __restrict__ norms,
    const float* __restrict__ rr, const float* __restrict__ ri,
    float* __restrict__ vr, float* __restrict__ vi)
{
  const int d = blockIdx.x * 256 + threadIdx.x;
  const int c = blockIdx.y;
  float wc = 0.1f * powf(0.9f, (float)(31 - c));
  float ar = 0.f, ai = 0.f;
  for (int k = 0; k < KB_; ++k) {
    float cf = coeffs[(c * KB_ + k) * D_MODEL + d];
    float cn = cf / norms[c * KB_ + k];
    ar += cn * rr[k * D_MODEL + d];
    ai += cn * ri[k * D_MODEL + d];
  }
  atomicAdd(&vr[d], wc * ar);
  atomicAdd(&vi[d], wc * ai);
}

// ---------------------------------------------------------------------------
// K5a: single block. cnorms EMA, top-8 of delta (stable), softplus weights,
// write vr/vi to d_out, ctx[d] into ws.
// ---------------------------------------------------------------------------
__global__ __launch_bounds__(256) void k5a_ctx(
    const float* __restrict__ norms, const float* __restrict__ vr_ws,
    const float* __restrict__ vi_ws, const float* __restrict__ rr,
    const float* __restrict__ ri, const float* __restrict__ wbands,
    float* __restrict__ dout, float* __restrict__ ctx)
{
  __shared__ float cn_s[64];
  __shared__ float del_s[64];
  __shared__ int top_s[8];
  __shared__ float wgt_s[8];
  const int tid = threadIdx.x;
  if (tid < 64) {
    float s = 0.f;
    for (int c = 0; c < NCHUNK; ++c) s = 0.9f * s + 0.1f * norms[c * KB_ + tid];
    cn_s[tid] = s;
    del_s[tid] = dout[D_MODEL + tid];
  }
  __syncthreads();
  if (tid == 0) {
    unsigned long long taken = 0ULL;
    for (int j = 0; j < 8; ++j) {
      float best = -1.f;
      int bi = 0;
      for (int k = 0; k < 64; ++k) {
        if (!((taken >> k) & 1ULL) && del_s[k] > best) { best = del_s[k]; bi = k; }
      }
      taken |= (1ULL << bi);
      top_s[j] = bi;
      wgt_s[j] = log1pf(expf(wbands[bi]));  // softplus
    }
  }
  __syncthreads();
  for (int d = tid; d < D_MODEL; d += 256) {
    float vr = vr_ws[d], vi = vi_ws[d];
    dout[D_MODEL + KB_ + d] = vr;
    dout[D_MODEL + KB_ + D_MODEL + d] = vi;
    float cx = 0.f;
#pragma unroll
    for (int j = 0; j < 8; ++j) {
      int k = top_s[j];
      cx += wgt_s[j] * (vr * rr[k * D_MODEL + d] + vi * ri[k * D_MODEL + d]) *
            fmaxf(cn_s[k], 1e-12f);
    }
    ctx[d] = cx;
  }
}

// ---------------------------------------------------------------------------
// K5b: out[d] = sigmoid(gate) * sum_e ctx[e]*Wp[d][e]; one wave per row
// ---------------------------------------------------------------------------
__global__ __launch_bounds__(256) void k5b_gemv(
    const float* __restrict__ Wp, const float* __restrict__ ctx,
    const float* __restrict__ gate, float* __restrict__ dout)
{
  const int tid = threadIdx.x;
  const int lane = tid & 63;
  const int w = tid >> 6;
  const int row = blockIdx.x * 4 + w;
  const float* p = Wp + row * D_MODEL;
  float s = 0.f;
#pragma unroll
  for (int i = 0; i < 8; ++i) {
    int e = lane * 4 + i * 256;
    float4 wv = *(const float4*)(p + e);
    float4 cv = *(const float4*)(ctx + e);
    s += wv.x * cv.x + wv.y * cv.y + wv.z * cv.z + wv.w * cv.w;
  }
  for (int o = 32; o > 0; o >>= 1) s += __shfl_down(s, o, 64);
  if (lane == 0) {
    float sig = 1.f / (1.f + expf(-gate[0]));
    dout[row] = s * sig;
  }
}

extern "C" void kernel_launch(void* const* d_in, const int* in_sizes, int n_in,
                              void* d_out, int out_size, void* d_ws, size_t ws_size,
                              hipStream_t stream) {
  const float* scan  = (const float*)d_in[0];
  const float* buf   = (const float*)d_in[1];
  const float* rr    = (const float*)d_in[2];
  const float* ri    = (const float*)d_in[3];
  const float* wb    = (const float*)d_in[4];
  const float* Wp    = (const float*)d_in[5];
  const float* gate  = (const float*)d_in[6];
  const float* cheby = (const float*)d_in[7];
  float* out = (float*)d_out;
  float* ws = (float*)d_ws;
  float* coeffs = ws;
  float* norms  = ws + OFF_NORMS;
  float* vr     = ws + OFF_VR;
  float* vi     = ws + OFF_VI;
  float* ctx    = ws + OFF_CTX;

  // zero vr/vi accumulators (contiguous)
  hipMemsetAsync(vr, 0, 2 * D_MODEL * sizeof(float), stream);

  k1_coeffs<<<dim3(16, NCHUNK), 256, 0, stream>>>(scan, buf, cheby, coeffs);
  k2_norms<<<NCHUNK * KB_ + KB_, 256, 0, stream>>>(coeffs, norms, out);
  k3_bind<<<dim3(8, NCHUNK), 256, 0, stream>>>(coeffs, norms, rr, ri, vr, vi);
  k5a_ctx<<<1, 256, 0, stream>>>(norms, vr, vi, rr, ri, wb, out, ctx);
  k5b_gemv<<<512, 256, 0, stream>>>(Wp, ctx, gate, out);
}

// Round 2
// 309.209 us; speedup vs baseline: 1.1412x; 1.1412x over previous
//
#include <hip/hip_runtime.h>
#include <math.h>

#define D_MODEL 2048
#define KB_ 64
#define NCHUNK 32

typedef __bf16 bf16;
typedef __attribute__((ext_vector_type(8))) __bf16 bf16x8;
typedef __attribute__((ext_vector_type(4))) __bf16 bf16x4;
typedef __attribute__((ext_vector_type(4))) float f32x4;

// ---- workspace layout (float offsets) ----
// PQ[33][128][2048] : PQ[j][b][d]; b<64: P_j (cheby cols 0:256) ; b>=64: Q_j (cheby cols 256:512)
//   data_j = (j==0 ? buf[256:512] : chunk_{j-1});  scale (incl. c0 halving) pre-applied.
#define OFF_PQ 0
#define N_PQ (33 * 128 * 2048)
#define OFF_CHEB2 N_PQ              // 32768 bf16 = 16384 floats
#define OFF_NORMS (N_PQ + 16384)    // 2048
#define OFF_PARTR (OFF_NORMS + 2048)       // 32*2048
#define OFF_PARTI (OFF_PARTR + 32 * 2048)  // 32*2048
#define OFF_VR (OFF_PARTI + 32 * 2048)
#define OFF_VI (OFF_VR + 2048)
#define OFF_CTX (OFF_VI + 2048)

// ---------------------------------------------------------------------------
// K0: cheb2[b][n] (bf16, [128][256]) = b<64 ? cheby[b][n] : cheby[b-64][256+n]
// ---------------------------------------------------------------------------
__global__ __launch_bounds__(256) void k0_prep(
    const float* __restrict__ cheby, bf16* __restrict__ cheb2)
{
  int flat = blockIdx.x * 256 + threadIdx.x;   // 0..32767
  int b = flat >> 8, n = flat & 255;
  float v = (b < 64) ? cheby[b * 512 + n] : cheby[(b - 64) * 512 + 256 + n];
  cheb2[flat] = (bf16)v;
}

// ---------------------------------------------------------------------------
// K1: per chunk j (0..32), d-tile (0..15): D[128 band][128 d] =
//     sum_n cheb2[band][n] * data_j[n][d0+d], scaled, -> PQ
// 256 threads = 4 waves (2x2), each wave 64x64 via 4x4 mfma 16x16x32 tiles.
// ---------------------------------------------------------------------------
__global__ __launch_bounds__(256, 2) void k1_mfma(
    const float* __restrict__ scan, const float* __restrict__ buf,
    const bf16* __restrict__ cheb2, float* __restrict__ PQ)
{
  __shared__ bf16 As[128 * 72];   // [band][72] (64 k-slots + pad)
  __shared__ bf16 Bs[128 * 72];   // [d][72]    (64 k-slots + pad) -- k = window-n within slice

  const int t = threadIdx.x;
  const int dtile = blockIdx.x, j = blockIdx.y;
  const int wid = t >> 6, lane = t & 63;
  const int wm = wid >> 1, wn = wid & 1;
  const int quad = lane >> 4, r16 = lane & 15;
  const int d0 = dtile * 128;
  const float* scan1 = scan + 8192 * 2048;

  f32x4 acc[4][4];
#pragma unroll
  for (int a = 0; a < 4; ++a)
#pragma unroll
    for (int b = 0; b < 4; ++b) acc[a][b] = (f32x4){0.f, 0.f, 0.f, 0.f};

  for (int nb = 0; nb < 4; ++nb) {
    __syncthreads();
    // stage A: 128 bands x 64 n (bf16), 16B chunks
#pragma unroll
    for (int i = 0; i < 4; ++i) {
      int flat = t + i * 256;          // 0..1023
      int b = flat >> 3, q8 = flat & 7;
      bf16x8 v = *(const bf16x8*)(cheb2 + b * 256 + nb * 64 + q8 * 8);
      *(bf16x8*)(As + b * 72 + q8 * 8) = v;
    }
    // stage B transposed: Bs[d][n]; each thread: 4 consecutive n for one d
#pragma unroll
    for (int i = 0; i < 8; ++i) {
      int p = t + i * 256;             // 0..2047
      int d = p & 127;
      int n0 = (p >> 7) * 4;           // 0,4,...,60
      float v[4];
      if (j == 0) {
#pragma unroll
        for (int x = 0; x < 4; ++x)
          v[x] = buf[(256 + nb * 64 + n0 + x) * 2048 + d0 + d];
      } else {
        int base = ((j - 1) * 256 + nb * 64 + n0) * 2048 + d0 + d;
#pragma unroll
        for (int x = 0; x < 4; ++x)
          v[x] = 0.5f * (scan[base + x * 2048] + scan1[base + x * 2048]);
      }
      bf16x4 e = {(bf16)v[0], (bf16)v[1], (bf16)v[2], (bf16)v[3]};
      *(bf16x4*)(Bs + d * 72 + n0) = e;
    }
    __syncthreads();

#pragma unroll
    for (int ks = 0; ks < 2; ++ks) {
      bf16x8 af[4], bfr[4];
#pragma unroll
      for (int tm = 0; tm < 4; ++tm)
        af[tm] = *(const bf16x8*)(As + (wm * 64 + tm * 16 + r16) * 72 + ks * 32 + quad * 8);
#pragma unroll
      for (int tn = 0; tn < 4; ++tn)
        bfr[tn] = *(const bf16x8*)(Bs + (wn * 64 + tn * 16 + r16) * 72 + ks * 32 + quad * 8);
#pragma unroll
      for (int tm = 0; tm < 4; ++tm)
#pragma unroll
        for (int tn = 0; tn < 4; ++tn)
          acc[tm][tn] = __builtin_amdgcn_mfma_f32_16x16x32_bf16(
              af[tm], bfr[tn], acc[tm][tn], 0, 0, 0);
    }
  }

  const float scale = 2.0f / 512.0f;
#pragma unroll
  for (int tm = 0; tm < 4; ++tm) {
    int band_base = wm * 64 + tm * 16 + quad * 4;
#pragma unroll
    for (int tn = 0; tn < 4; ++tn) {
      int dc = d0 + wn * 64 + tn * 16 + r16;
#pragma unroll
      for (int r = 0; r < 4; ++r) {
        int band = band_base + r;
        float sc = (band == 0 || band == 64) ? scale * 0.5f : scale;
        PQ[(j * 128 + band) * 2048 + dc] = acc[tm][tn][r] * sc;
      }
    }
  }
}

// ---------------------------------------------------------------------------
// K2: blocks 0..2047: norms[c][k] = max(||P[c][k]+Q[c+1][64+k]||, eps)
//     blocks 2048..2111: delta[k] -> d_out[2048..]
// ---------------------------------------------------------------------------
__global__ __launch_bounds__(256) void k2_norms(
    const float* __restrict__ PQ, float* __restrict__ norms,
    float* __restrict__ dout)
{
  const int tid = threadIdx.x;
  const int b = blockIdx.x;
  float s = 0.f;
  if (b < NCHUNK * KB_) {
    int c = b >> 6, k = b & 63;
    const float* P = PQ + (c * 128 + k) * 2048;
    const float* Q = PQ + ((c + 1) * 128 + 64 + k) * 2048;
#pragma unroll
    for (int i = 0; i < 2; ++i) {
      float4 p = *(const float4*)(P + tid * 4 + i * 1024);
      float4 q = *(const float4*)(Q + tid * 4 + i * 1024);
      float x = p.x + q.x, y = p.y + q.y, z = p.z + q.z, w = p.w + q.w;
      s += x * x + y * y + z * z + w * w;
    }
  } else {
    int k = b - NCHUNK * KB_;
    const float* P1 = PQ + (31 * 128 + k) * 2048;
    const float* Q2 = PQ + (32 * 128 + 64 + k) * 2048;
    const float* P0 = PQ + (30 * 128 + k) * 2048;
    const float* Q1 = PQ + (31 * 128 + 64 + k) * 2048;
#pragma unroll
    for (int i = 0; i < 2; ++i) {
      float4 a = *(const float4*)(P1 + tid * 4 + i * 1024);
      float4 bb = *(const float4*)(Q2 + tid * 4 + i * 1024);
      float4 cc = *(const float4*)(P0 + tid * 4 + i * 1024);
      float4 dd = *(const float4*)(Q1 + tid * 4 + i * 1024);
      float x = a.x + bb.x - cc.x - dd.x, y = a.y + bb.y - cc.y - dd.y;
      float z = a.z + bb.z - cc.z - dd.z, w = a.w + bb.w - cc.w - dd.w;
      s += x * x + y * y + z * z + w * w;
    }
  }
  for (int o = 32; o > 0; o >>= 1) s += __shfl_down(s, o, 64);
  __shared__ float red[4];
  if ((tid & 63) == 0) red[tid >> 6] = s;
  __syncthreads();
  if (tid == 0) {
    float r = sqrtf(red[0] + red[1] + red[2] + red[3]);
    if (b < NCHUNK * KB_) norms[b] = fmaxf(r, 1e-12f);
    else dout[D_MODEL + (b - NCHUNK * KB_)] = r;
  }
}

// ---------------------------------------------------------------------------
// K3: partial binds per (c, d): part_r/part_i[c][d] = wc * sum_k cn*role
// ---------------------------------------------------------------------------
__global__ __launch_bounds__(256) void k3_bind(
    const float* __restrict__ PQ, const float* __restrict__ norms,
    const float* __restrict__ rr, const float* __restrict__ ri,
    float* __restrict__ part_r, float* __restrict__ part_i)
{
  const int d = blockIdx.x * 256 + threadIdx.x;
  const int c = blockIdx.y;
  float wc = 0.1f * powf(0.9f, (float)(31 - c));
  float ar = 0.f, ai = 0.f;
  for (int k = 0; k < KB_; ++k) {
    float coeff = PQ[(c * 128 + k) * 2048 + d] + PQ[((c + 1) * 128 + 64 + k) * 2048 + d];
    float cn = coeff / norms[c * KB_ + k];
    ar += cn * rr[k * D_MODEL + d];
    ai += cn * ri[k * D_MODEL + d];
  }
  part_r[c * D_MODEL + d] = wc * ar;
  part_i[c * D_MODEL + d] = wc * ai;
}

// K3b: vr[d] = sum_c part_r[c][d]; vi likewise
__global__ __launch_bounds__(256) void k3b_reduce(
    const float* __restrict__ part_r, const float* __restrict__ part_i,
    float* __restrict__ vr, float* __restrict__ vi)
{
  const int d = blockIdx.x * 256 + threadIdx.x;
  float sr = 0.f, si = 0.f;
  for (int c = 0; c < NCHUNK; ++c) {
    sr += part_r[c * D_MODEL + d];
    si += part_i[c * D_MODEL + d];
  }
  vr[d] = sr;
  vi[d] = si;
}

// ---------------------------------------------------------------------------
// K5a: cnorms EMA, stable top-8 of delta, softplus weights, vr/vi out, ctx
// ---------------------------------------------------------------------------
__global__ __launch_bounds__(256) void k5a_ctx(
    const float* __restrict__ norms, const float* __restrict__ vr_ws,
    const float* __restrict__ vi_ws, const float* __restrict__ rr,
    const float* __restrict__ ri, const float* __restrict__ wbands,
    float* __restrict__ dout, float* __restrict__ ctx)
{
  __shared__ float cn_s[64];
  __shared__ float del_s[64];
  __shared__ int top_s[8];
  __shared__ float wgt_s[8];
  const int tid = threadIdx.x;
  if (tid < 64) {
    float s = 0.f;
    for (int c = 0; c < NCHUNK; ++c) s = 0.9f * s + 0.1f * norms[c * KB_ + tid];
    cn_s[tid] = s;
    del_s[tid] = dout[D_MODEL + tid];
  }
  __syncthreads();
  if (tid == 0) {
    unsigned long long taken = 0ULL;
    for (int jj = 0; jj < 8; ++jj) {
      float best = -1.f;
      int bi = 0;
      for (int k = 0; k < 64; ++k) {
        if (!((taken >> k) & 1ULL) && del_s[k] > best) { best = del_s[k]; bi = k; }
      }
      taken |= (1ULL << bi);
      top_s[jj] = bi;
      wgt_s[jj] = log1pf(expf(wbands[bi]));  // softplus
    }
  }
  __syncthreads();
  for (int d = tid; d < D_MODEL; d += 256) {
    float vr = vr_ws[d], vi = vi_ws[d];
    dout[D_MODEL + KB_ + d] = vr;
    dout[D_MODEL + KB_ + D_MODEL + d] = vi;
    float cx = 0.f;
#pragma unroll
    for (int jj = 0; jj < 8; ++jj) {
      int k = top_s[jj];
      cx += wgt_s[jj] * (vr * rr[k * D_MODEL + d] + vi * ri[k * D_MODEL + d]) *
            fmaxf(cn_s[k], 1e-12f);
    }
    ctx[d] = cx;
  }
}

// K5b: out[d] = sigmoid(gate) * sum_e ctx[e]*Wp[d][e]
__global__ __launch_bounds__(256) void k5b_gemv(
    const float* __restrict__ Wp, const float* __restrict__ ctx,
    const float* __restrict__ gate, float* __restrict__ dout)
{
  const int tid = threadIdx.x;
  const int lane = tid & 63;
  const int w = tid >> 6;
  const int row = blockIdx.x * 4 + w;
  const float* p = Wp + row * D_MODEL;
  float s = 0.f;
#pragma unroll
  for (int i = 0; i < 8; ++i) {
    int e = lane * 4 + i * 256;
    float4 wv = *(const float4*)(p + e);
    float4 cv = *(const float4*)(ctx + e);
    s += wv.x * cv.x + wv.y * cv.y + wv.z * cv.z + wv.w * cv.w;
  }
  for (int o = 32; o > 0; o >>= 1) s += __shfl_down(s, o, 64);
  if (lane == 0) {
    float sig = 1.f / (1.f + expf(-gate[0]));
    dout[row] = s * sig;
  }
}

extern "C" void kernel_launch(void* const* d_in, const int* in_sizes, int n_in,
                              void* d_out, int out_size, void* d_ws, size_t ws_size,
                              hipStream_t stream) {
  const float* scan  = (const float*)d_in[0];
  const float* buf   = (const float*)d_in[1];
  const float* rr    = (const float*)d_in[2];
  const float* ri    = (const float*)d_in[3];
  const float* wb    = (const float*)d_in[4];
  const float* Wp    = (const float*)d_in[5];
  const float* gate  = (const float*)d_in[6];
  const float* cheby = (const float*)d_in[7];
  float* out = (float*)d_out;
  float* ws = (float*)d_ws;

  float* PQ     = ws + OFF_PQ;
  bf16*  cheb2  = (bf16*)(ws + OFF_CHEB2);
  float* norms  = ws + OFF_NORMS;
  float* part_r = ws + OFF_PARTR;
  float* part_i = ws + OFF_PARTI;
  float* vr     = ws + OFF_VR;
  float* vi     = ws + OFF_VI;
  float* ctx    = ws + OFF_CTX;

  k0_prep<<<128, 256, 0, stream>>>(cheby, cheb2);
  k1_mfma<<<dim3(16, 33), 256, 0, stream>>>(scan, buf, cheb2, PQ);
  k2_norms<<<NCHUNK * KB_ + KB_, 256, 0, stream>>>(PQ, norms, out);
  k3_bind<<<dim3(8, NCHUNK), 256, 0, stream>>>(PQ, norms, rr, ri, part_r, part_i);
  k3b_reduce<<<8, 256, 0, stream>>>(part_r, part_i, vr, vi);
  k5a_ctx<<<1, 256, 0, stream>>>(norms, vr, vi, rr, ri, wb, out, ctx);
  k5b_gemv<<<512, 256, 0, stream>>>(Wp, ctx, gate, out);
}

// Round 3
// 301.850 us; speedup vs baseline: 1.1691x; 1.0244x over previous
//
#include <hip/hip_runtime.h>
#include <math.h>

#define D_MODEL 2048
#define KB_ 64
#define NCHUNK 32

typedef __bf16 bf16;
typedef __attribute__((ext_vector_type(8))) __bf16 bf16x8;
typedef __attribute__((ext_vector_type(4))) __bf16 bf16x4;
typedef __attribute__((ext_vector_type(4))) float f32x4;

// ---- workspace layout (float offsets) ----
// PQ[33][128][2048] : b<64: P_j (cheby cols 0:256); b>=64: Q_j (cols 256:512)
//   data_j = (j==0 ? buf[256:512] : chunk_{j-1}); scale (incl. c0 halving) applied.
#define OFF_PQ 0
#define N_PQ (33 * 128 * 2048)
#define OFF_NORMS N_PQ                     // 2048
#define OFF_PARTR (OFF_NORMS + 2048)       // 32*2048
#define OFF_PARTI (OFF_PARTR + 32 * 2048)  // 32*2048
#define OFF_CTX (OFF_PARTI + 32 * 2048)    // 2048

// ---------------------------------------------------------------------------
// K1: per chunk j (0..32), d-tile (0..15): PQ[j][band][d0+d] =
//     scale * sum_n cheb2[band][n] * data_j[n][d0+d]
// cheb2[band][n] = band<64 ? cheby[band][n] : cheby[band-64][256+n] (bf16, in LDS)
// 256 threads = 4 waves (2x2), each wave 64x64 via 4x4 mfma 16x16x32 tiles.
// ---------------------------------------------------------------------------
__global__ __launch_bounds__(256, 4) void k1_mfma(
    const float* __restrict__ scan, const float* __restrict__ buf,
    const float* __restrict__ cheby, float* __restrict__ PQ)
{
  __shared__ bf16 As[128 * 72];   // [band][72] (64 k-slots + pad)
  __shared__ bf16 Bs[128 * 72];   // [d][72]    (64 k-slots + pad)

  const int t = threadIdx.x;
  const int dtile = blockIdx.x, j = blockIdx.y;
  const int wid = t >> 6, lane = t & 63;
  const int wm = wid >> 1, wn = wid & 1;
  const int quad = lane >> 4, r16 = lane & 15;
  const int d0 = dtile * 128;
  const float* scan1 = scan + 8192 * 2048;

  f32x4 acc[4][4];
#pragma unroll
  for (int a = 0; a < 4; ++a)
#pragma unroll
    for (int b = 0; b < 4; ++b) acc[a][b] = (f32x4){0.f, 0.f, 0.f, 0.f};

  for (int nb = 0; nb < 4; ++nb) {
    __syncthreads();
    // stage A: 128 bands x 64 n, fp32 cheby -> bf16 (L2-resident source)
#pragma unroll
    for (int i = 0; i < 8; ++i) {
      int flat = t + i * 256;          // 0..2047
      int b = flat >> 4, q4 = flat & 15;
      const float* src = (b < 64) ? (cheby + b * 512 + nb * 64)
                                  : (cheby + (b - 64) * 512 + 256 + nb * 64);
      float4 v = *(const float4*)(src + q4 * 4);
      bf16x4 e = {(bf16)v.x, (bf16)v.y, (bf16)v.z, (bf16)v.w};
      *(bf16x4*)(As + b * 72 + q4 * 4) = e;
    }
    // stage B transposed: Bs[d][n]; each thread: 4 consecutive n for one d
#pragma unroll
    for (int i = 0; i < 8; ++i) {
      int p = t + i * 256;             // 0..2047
      int d = p & 127;
      int n0 = (p >> 7) * 4;           // 0,4,...,60
      float v[4];
      if (j == 0) {
#pragma unroll
        for (int x = 0; x < 4; ++x)
          v[x] = buf[(256 + nb * 64 + n0 + x) * 2048 + d0 + d];
      } else {
        int base = ((j - 1) * 256 + nb * 64 + n0) * 2048 + d0 + d;
#pragma unroll
        for (int x = 0; x < 4; ++x)
          v[x] = 0.5f * (scan[base + x * 2048] + scan1[base + x * 2048]);
      }
      bf16x4 e = {(bf16)v[0], (bf16)v[1], (bf16)v[2], (bf16)v[3]};
      *(bf16x4*)(Bs + d * 72 + n0) = e;
    }
    __syncthreads();

#pragma unroll
    for (int ks = 0; ks < 2; ++ks) {
      bf16x8 af[4], bfr[4];
#pragma unroll
      for (int tm = 0; tm < 4; ++tm)
        af[tm] = *(const bf16x8*)(As + (wm * 64 + tm * 16 + r16) * 72 + ks * 32 + quad * 8);
#pragma unroll
      for (int tn = 0; tn < 4; ++tn)
        bfr[tn] = *(const bf16x8*)(Bs + (wn * 64 + tn * 16 + r16) * 72 + ks * 32 + quad * 8);
#pragma unroll
      for (int tm = 0; tm < 4; ++tm)
#pragma unroll
        for (int tn = 0; tn < 4; ++tn)
          acc[tm][tn] = __builtin_amdgcn_mfma_f32_16x16x32_bf16(
              af[tm], bfr[tn], acc[tm][tn], 0, 0, 0);
    }
  }

  const float scale = 2.0f / 512.0f;
#pragma unroll
  for (int tm = 0; tm < 4; ++tm) {
    int band_base = wm * 64 + tm * 16 + quad * 4;
#pragma unroll
    for (int tn = 0; tn < 4; ++tn) {
      int dc = d0 + wn * 64 + tn * 16 + r16;
#pragma unroll
      for (int r = 0; r < 4; ++r) {
        int band = band_base + r;
        float sc = (band == 0 || band == 64) ? scale * 0.5f : scale;
        PQ[(j * 128 + band) * 2048 + dc] = acc[tm][tn][r] * sc;
      }
    }
  }
}

// ---------------------------------------------------------------------------
// K2: blocks 0..2047: norms[c][k] = max(||P[c][k]+Q[c+1][64+k]||, eps)
//     blocks 2048..2111: delta[k] -> d_out[2048..]
// ---------------------------------------------------------------------------
__global__ __launch_bounds__(256) void k2_norms(
    const float* __restrict__ PQ, float* __restrict__ norms,
    float* __restrict__ dout)
{
  const int tid = threadIdx.x;
  const int b = blockIdx.x;
  float s = 0.f;
  if (b < NCHUNK * KB_) {
    int c = b >> 6, k = b & 63;
    const float* P = PQ + (c * 128 + k) * 2048;
    const float* Q = PQ + ((c + 1) * 128 + 64 + k) * 2048;
#pragma unroll
    for (int i = 0; i < 2; ++i) {
      float4 p = *(const float4*)(P + tid * 4 + i * 1024);
      float4 q = *(const float4*)(Q + tid * 4 + i * 1024);
      float x = p.x + q.x, y = p.y + q.y, z = p.z + q.z, w = p.w + q.w;
      s += x * x + y * y + z * z + w * w;
    }
  } else {
    int k = b - NCHUNK * KB_;
    const float* P1 = PQ + (31 * 128 + k) * 2048;
    const float* Q2 = PQ + (32 * 128 + 64 + k) * 2048;
    const float* P0 = PQ + (30 * 128 + k) * 2048;
    const float* Q1 = PQ + (31 * 128 + 64 + k) * 2048;
#pragma unroll
    for (int i = 0; i < 2; ++i) {
      float4 a = *(const float4*)(P1 + tid * 4 + i * 1024);
      float4 bb = *(const float4*)(Q2 + tid * 4 + i * 1024);
      float4 cc = *(const float4*)(P0 + tid * 4 + i * 1024);
      float4 dd = *(const float4*)(Q1 + tid * 4 + i * 1024);
      float x = a.x + bb.x - cc.x - dd.x, y = a.y + bb.y - cc.y - dd.y;
      float z = a.z + bb.z - cc.z - dd.z, w = a.w + bb.w - cc.w - dd.w;
      s += x * x + y * y + z * z + w * w;
    }
  }
  for (int o = 32; o > 0; o >>= 1) s += __shfl_down(s, o, 64);
  __shared__ float red[4];
  if ((tid & 63) == 0) red[tid >> 6] = s;
  __syncthreads();
  if (tid == 0) {
    float r = sqrtf(red[0] + red[1] + red[2] + red[3]);
    if (b < NCHUNK * KB_) norms[b] = fmaxf(r, 1e-12f);
    else dout[D_MODEL + (b - NCHUNK * KB_)] = r;
  }
}

// ---------------------------------------------------------------------------
// K3: partial binds: part_r/i[c][d] = wc * sum_k (coeff/norm)*role, float4/d
// grid: (2 d-tiles of 1024, 32 c)
// ---------------------------------------------------------------------------
__global__ __launch_bounds__(256) void k3_bind(
    const float* __restrict__ PQ, const float* __restrict__ norms,
    const float* __restrict__ rr, const float* __restrict__ ri,
    float* __restrict__ part_r, float* __restrict__ part_i)
{
  const int d4 = (blockIdx.x * 256 + threadIdx.x) * 4;
  const int c = blockIdx.y;
  const float wc = 0.1f * powf(0.9f, (float)(31 - c));
  float4 ar = make_float4(0.f, 0.f, 0.f, 0.f);
  float4 ai = make_float4(0.f, 0.f, 0.f, 0.f);
  for (int k = 0; k < KB_; ++k) {
    float4 p = *(const float4*)(PQ + (c * 128 + k) * 2048 + d4);
    float4 q = *(const float4*)(PQ + ((c + 1) * 128 + 64 + k) * 2048 + d4);
    float inv = 1.0f / norms[c * KB_ + k];
    float4 r = *(const float4*)(rr + k * D_MODEL + d4);
    float4 im = *(const float4*)(ri + k * D_MODEL + d4);
    float cx = (p.x + q.x) * inv, cy = (p.y + q.y) * inv;
    float cz = (p.z + q.z) * inv, cw = (p.w + q.w) * inv;
    ar.x += cx * r.x; ar.y += cy * r.y; ar.z += cz * r.z; ar.w += cw * r.w;
    ai.x += cx * im.x; ai.y += cy * im.y; ai.z += cz * im.z; ai.w += cw * im.w;
  }
  float4 outr = make_float4(wc * ar.x, wc * ar.y, wc * ar.z, wc * ar.w);
  float4 outi = make_float4(wc * ai.x, wc * ai.y, wc * ai.z, wc * ai.w);
  *(float4*)(part_r + c * D_MODEL + d4) = outr;
  *(float4*)(part_i + c * D_MODEL + d4) = outi;
}

// ---------------------------------------------------------------------------
// K4 (merged k3b+k5a): per block (8 x 256): cnorms EMA + top-8 (redundant,
// cheap), c-sum of partials -> vr/vi -> d_out, ctx -> ws
// ---------------------------------------------------------------------------
__global__ __launch_bounds__(256) void k4_ctx(
    const float* __restrict__ norms, const float* __restrict__ part_r,
    const float* __restrict__ part_i, const float* __restrict__ rr,
    const float* __restrict__ ri, const float* __restrict__ wbands,
    float* __restrict__ dout, float* __restrict__ ctx)
{
  __shared__ float cn_s[64];
  __shared__ int top_s[8];
  __shared__ float wgt_s[8];
  const int tid = threadIdx.x;
  const int d = blockIdx.x * 256 + tid;
  if (tid < 64) {
    float s = 0.f;
    for (int c = 0; c < NCHUNK; ++c) s = 0.9f * s + 0.1f * norms[c * KB_ + tid];
    cn_s[tid] = fmaxf(s, 1e-12f);
  }
  __syncthreads();
  if (tid == 0) {
    unsigned long long taken = 0ULL;
    for (int jj = 0; jj < 8; ++jj) {
      float best = -1.f;
      int bi = 0;
      for (int k = 0; k < 64; ++k) {
        float dv = dout[D_MODEL + k];
        if (!((taken >> k) & 1ULL) && dv > best) { best = dv; bi = k; }
      }
      taken |= (1ULL << bi);
      top_s[jj] = bi;
      wgt_s[jj] = log1pf(expf(wbands[bi]));  // softplus
    }
  }
  __syncthreads();
  float sr = 0.f, si = 0.f;
  for (int c = 0; c < NCHUNK; ++c) {
    sr += part_r[c * D_MODEL + d];
    si += part_i[c * D_MODEL + d];
  }
  dout[D_MODEL + KB_ + d] = sr;
  dout[D_MODEL + KB_ + D_MODEL + d] = si;
  float cx = 0.f;
#pragma unroll
  for (int jj = 0; jj < 8; ++jj) {
    int k = top_s[jj];
    cx += wgt_s[jj] * (sr * rr[k * D_MODEL + d] + si * ri[k * D_MODEL + d]) * cn_s[k];
  }
  ctx[d] = cx;
}

// K5b: out[d] = sigmoid(gate) * sum_e ctx[e]*Wp[d][e]; one wave per row
__global__ __launch_bounds__(256) void k5b_gemv(
    const float* __restrict__ Wp, const float* __restrict__ ctx,
    const float* __restrict__ gate, float* __restrict__ dout)
{
  const int tid = threadIdx.x;
  const int lane = tid & 63;
  const int w = tid >> 6;
  const int row = blockIdx.x * 4 + w;
  const float* p = Wp + row * D_MODEL;
  float s = 0.f;
#pragma unroll
  for (int i = 0; i < 8; ++i) {
    int e = lane * 4 + i * 256;
    float4 wv = *(const float4*)(p + e);
    float4 cv = *(const float4*)(ctx + e);
    s += wv.x * cv.x + wv.y * cv.y + wv.z * cv.z + wv.w * cv.w;
  }
  for (int o = 32; o > 0; o >>= 1) s += __shfl_down(s, o, 64);
  if (lane == 0) {
    float sig = 1.f / (1.f + expf(-gate[0]));
    dout[row] = s * sig;
  }
}

extern "C" void kernel_launch(void* const* d_in, const int* in_sizes, int n_in,
                              void* d_out, int out_size, void* d_ws, size_t ws_size,
                              hipStream_t stream) {
  const float* scan  = (const float*)d_in[0];
  const float* buf   = (const float*)d_in[1];
  const float* rr    = (const float*)d_in[2];
  const float* ri    = (const float*)d_in[3];
  const float* wb    = (const float*)d_in[4];
  const float* Wp    = (const float*)d_in[5];
  const float* gate  = (const float*)d_in[6];
  const float* cheby = (const float*)d_in[7];
  float* out = (float*)d_out;
  float* ws = (float*)d_ws;

  float* PQ     = ws + OFF_PQ;
  float* norms  = ws + OFF_NORMS;
  float* part_r = ws + OFF_PARTR;
  float* part_i = ws + OFF_PARTI;
  float* ctx    = ws + OFF_CTX;

  k1_mfma<<<dim3(16, 33), 256, 0, stream>>>(scan, buf, cheby, PQ);
  k2_norms<<<NCHUNK * KB_ + KB_, 256, 0, stream>>>(PQ, norms, out);
  k3_bind<<<dim3(2, NCHUNK), 256, 0, stream>>>(PQ, norms, rr, ri, part_r, part_i);
  k4_ctx<<<8, 256, 0, stream>>>(norms, part_r, part_i, rr, ri, wb, out, ctx);
  k5b_gemv<<<512, 256, 0, stream>>>(Wp, ctx, gate, out);
}

// Round 4
// 279.565 us; speedup vs baseline: 1.2622x; 1.0797x over previous
//
#include <hip/hip_runtime.h>
#include <math.h>

#define D_MODEL 2048
#define KB_ 64
#define NCHUNK 32

typedef __bf16 bf16;
typedef __attribute__((ext_vector_type(8))) __bf16 bf16x8;
typedef __attribute__((ext_vector_type(4))) __bf16 bf16x4;
typedef __attribute__((ext_vector_type(4))) float f32x4;

// ---- workspace layout (float offsets) ----
#define OFF_COEFFS 0                           // [32][64][2048]
#define OFF_NSQ    (32 * 64 * 2048)            // [32][64][32] per-dtile sumsq partials
#define OFF_NORMS  (OFF_NSQ + 32 * 64 * 32)    // [32][64] final norms
#define OFF_PARTR  (OFF_NORMS + 2048)          // [32][2048]
#define OFF_PARTI  (OFF_PARTR + 32 * 2048)     // [32][2048]
#define OFF_CTX    (OFF_PARTI + 32 * 2048)     // [2048]
#define OFF_CHEB2  (OFF_CTX + 2048)            // 32768 bf16 = 16384 floats

// ---------------------------------------------------------------------------
// K0: cheb2 = bf16(cheby), same [64][512] layout
// ---------------------------------------------------------------------------
__global__ __launch_bounds__(256) void k0_prep(
    const float* __restrict__ cheby, bf16* __restrict__ cheb2)
{
  int flat = blockIdx.x * 256 + threadIdx.x;   // 0..32767
  cheb2[flat] = (bf16)cheby[flat];
}

// ---------------------------------------------------------------------------
// K1: window form. Block (dt, c): coeffs[c][band][d0..d0+64) =
//   scale * sum_{n=0..511} cheby[band][n] * window_c[n][d]
// window_c = [chunk_{c-1} (or buf[256:512] if c==0); chunk_c]
// 4 waves; wave w: bands [w*16,(w+1)*16) x 64 d, acc = 4 x f32x4.
// Also writes nsq_part[c][band][dt] = sum_d coeffs^2 over this d-tile.
// ---------------------------------------------------------------------------
__global__ __launch_bounds__(256) void k1_mfma(
    const float* __restrict__ scan, const float* __restrict__ buf,
    const bf16* __restrict__ cheb2, float* __restrict__ coeffs,
    float* __restrict__ nsq_part)
{
  __shared__ bf16 Bs[64 * 72];   // [d][72]: 64 n-slots + pad

  const int t = threadIdx.x;
  const int dt = blockIdx.x;     // 0..31 d-tile
  const int c  = blockIdx.y;     // 0..31 window
  const int w = t >> 6, lane = t & 63;
  const int quad = lane >> 4, r16 = lane & 15;
  const int d0 = dt * 64;
  const int n0 = (t >> 4) * 4;   // staging: 4 n-rows per thread
  const int d4 = (t & 15) * 4;   // staging: 4 d-cols per thread
  const float* scan1 = scan + 8192 * 2048;

  f32x4 acc[4];
#pragma unroll
  for (int tn = 0; tn < 4; ++tn) acc[tn] = (f32x4){0.f, 0.f, 0.f, 0.f};

  for (int nb = 0; nb < 8; ++nb) {
    // A-fragments straight from L2-resident bf16 cheby
    const bf16* abase = cheb2 + (w * 16 + r16) * 512 + nb * 64 + quad * 8;
    bf16x8 a0 = *(const bf16x8*)(abase);
    bf16x8 a1 = *(const bf16x8*)(abase + 32);

    // B staging: rows n0..n0+3, cols d4..d4+3 of this 64x64 slice
    float vv[4][4];
    if (c == 0 && nb < 4) {
      const float* bp = buf + (256 + nb * 64 + n0) * 2048 + d0 + d4;
#pragma unroll
      for (int i = 0; i < 4; ++i) {
        float4 v = *(const float4*)(bp + i * 2048);
        vv[i][0] = v.x; vv[i][1] = v.y; vv[i][2] = v.z; vv[i][3] = v.w;
      }
    } else {
      int gbase = (c * 256 - 256 + nb * 64 + n0) * 2048 + d0 + d4;
#pragma unroll
      for (int i = 0; i < 4; ++i) {
        float4 a = *(const float4*)(scan + gbase + i * 2048);
        float4 b = *(const float4*)(scan1 + gbase + i * 2048);
        vv[i][0] = 0.5f * (a.x + b.x); vv[i][1] = 0.5f * (a.y + b.y);
        vv[i][2] = 0.5f * (a.z + b.z); vv[i][3] = 0.5f * (a.w + b.w);
      }
    }
    __syncthreads();   // previous iteration's reads done before overwrite
#pragma unroll
    for (int x = 0; x < 4; ++x) {
      bf16x4 e = {(bf16)vv[0][x], (bf16)vv[1][x], (bf16)vv[2][x], (bf16)vv[3][x]};
      *(bf16x4*)(Bs + (d4 + x) * 72 + n0) = e;
    }
    __syncthreads();

#pragma unroll
    for (int ks = 0; ks < 2; ++ks) {
      bf16x8 a = ks ? a1 : a0;
#pragma unroll
      for (int tn = 0; tn < 4; ++tn) {
        bf16x8 bfr = *(const bf16x8*)(Bs + (tn * 16 + r16) * 72 + ks * 32 + quad * 8);
        acc[tn] = __builtin_amdgcn_mfma_f32_16x16x32_bf16(a, bfr, acc[tn], 0, 0, 0);
      }
    }
  }

  // epilogue: scale, store, per-band sumsq partial
  const float scale = 2.0f / 512.0f;
  float sq[4] = {0.f, 0.f, 0.f, 0.f};
#pragma unroll
  for (int tn = 0; tn < 4; ++tn) {
#pragma unroll
    for (int rr = 0; rr < 4; ++rr) {
      int band = w * 16 + quad * 4 + rr;
      float sc = (band == 0) ? scale * 0.5f : scale;
      float v = acc[tn][rr] * sc;
      coeffs[(c * 64 + band) * 2048 + d0 + tn * 16 + r16] = v;
      sq[rr] += v * v;
    }
  }
#pragma unroll
  for (int off = 8; off > 0; off >>= 1) {
#pragma unroll
    for (int rr = 0; rr < 4; ++rr) sq[rr] += __shfl_down(sq[rr], off);
  }
  if (r16 == 0) {
#pragma unroll
    for (int rr = 0; rr < 4; ++rr)
      nsq_part[(c * 64 + w * 16 + quad * 4 + rr) * 32 + dt] = sq[rr];
  }
}

// ---------------------------------------------------------------------------
// KD: delta[k] = ||coeffs[31][k] - coeffs[30][k]|| -> dout[2048+k]
// ---------------------------------------------------------------------------
__global__ __launch_bounds__(256) void kd_delta(
    const float* __restrict__ coeffs, float* __restrict__ dout)
{
  const int k = blockIdx.x, tid = threadIdx.x;
  const float* p1 = coeffs + (31 * 64 + k) * 2048;
  const float* p0 = coeffs + (30 * 64 + k) * 2048;
  float s = 0.f;
#pragma unroll
  for (int i = 0; i < 2; ++i) {
    float4 a = *(const float4*)(p1 + tid * 4 + i * 1024);
    float4 b = *(const float4*)(p0 + tid * 4 + i * 1024);
    float x = a.x - b.x, y = a.y - b.y, z = a.z - b.z, ww = a.w - b.w;
    s += x * x + y * y + z * z + ww * ww;
  }
  for (int o = 32; o > 0; o >>= 1) s += __shfl_down(s, o, 64);
  __shared__ float red[4];
  if ((tid & 63) == 0) red[tid >> 6] = s;
  __syncthreads();
  if (tid == 0) dout[D_MODEL + k] = sqrtf(red[0] + red[1] + red[2] + red[3]);
}

// ---------------------------------------------------------------------------
// K3: finalize norms (from nsq_part) + partial binds per (c, d-half)
// grid (2, 32). blockIdx.x==0 block also writes norms[c][*] for k4.
// ---------------------------------------------------------------------------
__global__ __launch_bounds__(256) void k3_bind(
    const float* __restrict__ coeffs, const float* __restrict__ nsq_part,
    const float* __restrict__ rr, const float* __restrict__ ri,
    float* __restrict__ part_r, float* __restrict__ part_i,
    float* __restrict__ norms)
{
  __shared__ float inv_s[64];
  const int tid = threadIdx.x;
  const int c = blockIdx.y;
  if (tid < 64) {
    float s = 0.f;
#pragma unroll
    for (int dt = 0; dt < 32; ++dt) s += nsq_part[(c * 64 + tid) * 32 + dt];
    float nrm = fmaxf(sqrtf(s), 1e-12f);
    inv_s[tid] = 1.0f / nrm;
    if (blockIdx.x == 0) norms[c * 64 + tid] = nrm;
  }
  __syncthreads();
  const int d4 = (blockIdx.x * 256 + tid) * 4;
  const float wc = 0.1f * powf(0.9f, (float)(31 - c));
  float4 ar = make_float4(0.f, 0.f, 0.f, 0.f);
  float4 ai = make_float4(0.f, 0.f, 0.f, 0.f);
  for (int k = 0; k < KB_; ++k) {
    float4 cf = *(const float4*)(coeffs + (c * 64 + k) * 2048 + d4);
    float inv = inv_s[k];
    float4 r = *(const float4*)(rr + k * D_MODEL + d4);
    float4 im = *(const float4*)(ri + k * D_MODEL + d4);
    float cx = cf.x * inv, cy = cf.y * inv, cz = cf.z * inv, cw = cf.w * inv;
    ar.x += cx * r.x; ar.y += cy * r.y; ar.z += cz * r.z; ar.w += cw * r.w;
    ai.x += cx * im.x; ai.y += cy * im.y; ai.z += cz * im.z; ai.w += cw * im.w;
  }
  *(float4*)(part_r + c * D_MODEL + d4) =
      make_float4(wc * ar.x, wc * ar.y, wc * ar.z, wc * ar.w);
  *(float4*)(part_i + c * D_MODEL + d4) =
      make_float4(wc * ai.x, wc * ai.y, wc * ai.z, wc * ai.w);
}

// ---------------------------------------------------------------------------
// K4: cnorms EMA + top-8 (redundant per block, cheap), vr/vi -> d_out, ctx
// ---------------------------------------------------------------------------
__global__ __launch_bounds__(256) void k4_ctx(
    const float* __restrict__ norms, const float* __restrict__ part_r,
    const float* __restrict__ part_i, const float* __restrict__ rr,
    const float* __restrict__ ri, const float* __restrict__ wbands,
    float* __restrict__ dout, float* __restrict__ ctx)
{
  __shared__ float cn_s[64];
  __shared__ int top_s[8];
  __shared__ float wgt_s[8];
  const int tid = threadIdx.x;
  const int d = blockIdx.x * 256 + tid;
  if (tid < 64) {
    float s = 0.f;
    for (int c = 0; c < NCHUNK; ++c) s = 0.9f * s + 0.1f * norms[c * 64 + tid];
    cn_s[tid] = fmaxf(s, 1e-12f);
  }
  __syncthreads();
  if (tid == 0) {
    unsigned long long taken = 0ULL;
    for (int jj = 0; jj < 8; ++jj) {
      float best = -1.f;
      int bi = 0;
      for (int k = 0; k < 64; ++k) {
        float dv = dout[D_MODEL + k];
        if (!((taken >> k) & 1ULL) && dv > best) { best = dv; bi = k; }
      }
      taken |= (1ULL << bi);
      top_s[jj] = bi;
      wgt_s[jj] = log1pf(expf(wbands[bi]));  // softplus
    }
  }
  __syncthreads();
  float sr = 0.f, si = 0.f;
  for (int c = 0; c < NCHUNK; ++c) {
    sr += part_r[c * D_MODEL + d];
    si += part_i[c * D_MODEL + d];
  }
  dout[D_MODEL + KB_ + d] = sr;
  dout[D_MODEL + KB_ + D_MODEL + d] = si;
  float cx = 0.f;
#pragma unroll
  for (int jj = 0; jj < 8; ++jj) {
    int k = top_s[jj];
    cx += wgt_s[jj] * (sr * rr[k * D_MODEL + d] + si * ri[k * D_MODEL + d]) * cn_s[k];
  }
  ctx[d] = cx;
}

// K5b: out[d] = sigmoid(gate) * sum_e ctx[e]*Wp[d][e]; one wave per row
__global__ __launch_bounds__(256) void k5b_gemv(
    const float* __restrict__ Wp, const float* __restrict__ ctx,
    const float* __restrict__ gate, float* __restrict__ dout)
{
  const int tid = threadIdx.x;
  const int lane = tid & 63;
  const int w = tid >> 6;
  const int row = blockIdx.x * 4 + w;
  const float* p = Wp + row * D_MODEL;
  float s = 0.f;
#pragma unroll
  for (int i = 0; i < 8; ++i) {
    int e = lane * 4 + i * 256;
    float4 wv = *(const float4*)(p + e);
    float4 cv = *(const float4*)(ctx + e);
    s += wv.x * cv.x + wv.y * cv.y + wv.z * cv.z + wv.w * cv.w;
  }
  for (int o = 32; o > 0; o >>= 1) s += __shfl_down(s, o, 64);
  if (lane == 0) {
    float sig = 1.f / (1.f + expf(-gate[0]));
    dout[row] = s * sig;
  }
}

extern "C" void kernel_launch(void* const* d_in, const int* in_sizes, int n_in,
                              void* d_out, int out_size, void* d_ws, size_t ws_size,
                              hipStream_t stream) {
  const float* scan  = (const float*)d_in[0];
  const float* buf   = (const float*)d_in[1];
  const float* rr    = (const float*)d_in[2];
  const float* ri    = (const float*)d_in[3];
  const float* wb    = (const float*)d_in[4];
  const float* Wp    = (const float*)d_in[5];
  const float* gate  = (const float*)d_in[6];
  const float* cheby = (const float*)d_in[7];
  float* out = (float*)d_out;
  float* ws = (float*)d_ws;

  float* coeffs   = ws + OFF_COEFFS;
  float* nsq_part = ws + OFF_NSQ;
  float* norms    = ws + OFF_NORMS;
  float* part_r   = ws + OFF_PARTR;
  float* part_i   = ws + OFF_PARTI;
  float* ctx      = ws + OFF_CTX;
  bf16*  cheb2    = (bf16*)(ws + OFF_CHEB2);

  k0_prep<<<128, 256, 0, stream>>>(cheby, cheb2);
  k1_mfma<<<dim3(32, 32), 256, 0, stream>>>(scan, buf, cheb2, coeffs, nsq_part);
  kd_delta<<<64, 256, 0, stream>>>(coeffs, out);
  k3_bind<<<dim3(2, NCHUNK), 256, 0, stream>>>(coeffs, nsq_part, rr, ri,
                                               part_r, part_i, norms);
  k4_ctx<<<8, 256, 0, stream>>>(norms, part_r, part_i, rr, ri, wb, out, ctx);
  k5b_gemv<<<512, 256, 0, stream>>>(Wp, ctx, gate, out);
}